// Round 1
// baseline (616.970 us; speedup 1.0000x reference)
//
#include <hip/hip_runtime.h>

// NeuMF fused inference, fp32-exact.
// One thread = one sample. Weights (W1 16KB, W2 8KB, Wo, biases) are read with
// wave-uniform indices -> compiler emits scalar s_load broadcasts (no LDS, no
// VALU cost for weight movement). Embedding gathers are per-lane float4 loads.

#define MF_DIM 16
#define MLP_DIM 32

__global__ __launch_bounds__(256) void neumf_fused(
    const int* __restrict__ user, const int* __restrict__ item,
    const float* __restrict__ mf_user_tbl, const float* __restrict__ mf_item_tbl,
    const float* __restrict__ mlp_user_tbl, const float* __restrict__ mlp_item_tbl,
    const float* __restrict__ W1, const float* __restrict__ b1,
    const float* __restrict__ W2, const float* __restrict__ b2,
    const float* __restrict__ Wo, const float* __restrict__ bo,
    float* __restrict__ out, int n)
{
    const int s = blockIdx.x * 256 + threadIdx.x;
    if (s >= n) return;
    const int u  = user[s];
    const int it = item[s];

    // ---- GMF branch, immediately reduced against Wo[0:16] (keeps 1 live reg) ----
    const float4* fu = (const float4*)(mf_user_tbl + (size_t)u  * MF_DIM);
    const float4* fi = (const float4*)(mf_item_tbl + (size_t)it * MF_DIM);
    float pmf = bo[0];
    #pragma unroll
    for (int q = 0; q < 4; ++q) {
        const float4 a4 = fu[q];
        const float4 b4 = fi[q];
        pmf = fmaf(a4.x * b4.x, Wo[4*q + 0], pmf);
        pmf = fmaf(a4.y * b4.y, Wo[4*q + 1], pmf);
        pmf = fmaf(a4.z * b4.z, Wo[4*q + 2], pmf);
        pmf = fmaf(a4.w * b4.w, Wo[4*q + 3], pmf);
    }

    // ---- MLP layer 1: h = relu(concat(u_emb, i_emb) @ W1 + b1), W1 is [64,64] ----
    float h[64];
    #pragma unroll
    for (int j = 0; j < 64; ++j) h[j] = b1[j];

    // user half: rows 0..31 of W1
    {
        const float4* src = (const float4*)(mlp_user_tbl + (size_t)u * MLP_DIM);
        const float4 v0 = src[0], v1 = src[1], v2 = src[2], v3 = src[3];
        const float4 v4 = src[4], v5 = src[5], v6 = src[6], v7 = src[7];
        const float a[32] = { v0.x,v0.y,v0.z,v0.w, v1.x,v1.y,v1.z,v1.w,
                              v2.x,v2.y,v2.z,v2.w, v3.x,v3.y,v3.z,v3.w,
                              v4.x,v4.y,v4.z,v4.w, v5.x,v5.y,v5.z,v5.w,
                              v6.x,v6.y,v6.z,v6.w, v7.x,v7.y,v7.z,v7.w };
        #pragma unroll
        for (int k = 0; k < 32; ++k) {
            #pragma unroll
            for (int j = 0; j < 64; ++j)
                h[j] = fmaf(a[k], W1[k*64 + j], h[j]);
        }
    }
    // item half: rows 32..63 of W1
    {
        const float4* src = (const float4*)(mlp_item_tbl + (size_t)it * MLP_DIM);
        const float4 v0 = src[0], v1 = src[1], v2 = src[2], v3 = src[3];
        const float4 v4 = src[4], v5 = src[5], v6 = src[6], v7 = src[7];
        const float a[32] = { v0.x,v0.y,v0.z,v0.w, v1.x,v1.y,v1.z,v1.w,
                              v2.x,v2.y,v2.z,v2.w, v3.x,v3.y,v3.z,v3.w,
                              v4.x,v4.y,v4.z,v4.w, v5.x,v5.y,v5.z,v5.w,
                              v6.x,v6.y,v6.z,v6.w, v7.x,v7.y,v7.z,v7.w };
        #pragma unroll
        for (int k = 0; k < 32; ++k) {
            #pragma unroll
            for (int j = 0; j < 64; ++j)
                h[j] = fmaf(a[k], W1[(32 + k)*64 + j], h[j]);
        }
    }
    #pragma unroll
    for (int j = 0; j < 64; ++j) h[j] = fmaxf(h[j], 0.0f);

    // ---- MLP layer 2: h2 = relu(h @ W2 + b2), W2 is [64,32] ----
    float h2[32];
    #pragma unroll
    for (int j = 0; j < 32; ++j) h2[j] = b2[j];
    #pragma unroll
    for (int k = 0; k < 64; ++k) {
        #pragma unroll
        for (int j = 0; j < 32; ++j)
            h2[j] = fmaf(h[k], W2[k*32 + j], h2[j]);
    }

    // ---- output: pmf + relu(h2) . Wo[16:48] ----
    float acc = pmf;
    #pragma unroll
    for (int j = 0; j < 32; ++j)
        acc = fmaf(fmaxf(h2[j], 0.0f), Wo[16 + j], acc);

    out[s] = acc;
}

extern "C" void kernel_launch(void* const* d_in, const int* in_sizes, int n_in,
                              void* d_out, int out_size, void* d_ws, size_t ws_size,
                              hipStream_t stream) {
    const int*   user = (const int*)  d_in[0];
    const int*   item = (const int*)  d_in[1];
    const float* mfu  = (const float*)d_in[2];
    const float* mfi  = (const float*)d_in[3];
    const float* mlu  = (const float*)d_in[4];
    const float* mli  = (const float*)d_in[5];
    const float* W1   = (const float*)d_in[6];
    const float* b1   = (const float*)d_in[7];
    const float* W2   = (const float*)d_in[8];
    const float* b2   = (const float*)d_in[9];
    const float* Wo   = (const float*)d_in[10];
    const float* bo   = (const float*)d_in[11];
    float* out = (float*)d_out;

    const int n = in_sizes[0];
    const int blocks = (n + 255) / 256;
    neumf_fused<<<blocks, 256, 0, stream>>>(user, item, mfu, mfi, mlu, mli,
                                            W1, b1, W2, b2, Wo, bo, out, n);
}

// Round 2
// 503.755 us; speedup vs baseline: 1.2247x; 1.2247x over previous
//
#include <hip/hip_runtime.h>

// NeuMF fused inference, fp32-exact, restructured for I$-resident rolled loops
// and wave-uniform scalar weight streaming.
//
// Kernel A: transpose W2 [64,32] -> W2T [32,64] into d_ws (8 KB) so the
//           layer-2 j-rolled loop reads contiguous 64-float rows via s_load.
// Kernel B: one thread per sample. Activations are re-read from global in
//           4-row chunks (L1-hot after first touch; no extra HBM traffic),
//           avoiding both dynamic register indexing and a 96-reg array.

#define TPB 256

__global__ __launch_bounds__(64) void w2_transpose(const float* __restrict__ W2,
                                                   float* __restrict__ W2T) {
    const int t = threadIdx.x;               // 64 threads, 2048 elements
    #pragma unroll
    for (int i = 0; i < 32; ++i) {
        const int idx = i * 64 + t;          // flat over W2 (k*32+j)
        const int k = idx >> 5, j = idx & 31;
        W2T[j * 64 + k] = W2[idx];
    }
}

__global__ __launch_bounds__(TPB) void neumf_fused(
    const int* __restrict__ user, const int* __restrict__ item,
    const float* __restrict__ mf_user_tbl, const float* __restrict__ mf_item_tbl,
    const float* __restrict__ mlp_user_tbl, const float* __restrict__ mlp_item_tbl,
    const float* __restrict__ W1, const float* __restrict__ b1,
    const float* __restrict__ W2T, const float* __restrict__ b2,
    const float* __restrict__ Wo, const float* __restrict__ bo,
    float* __restrict__ out, int n)
{
    const int s = blockIdx.x * TPB + threadIdx.x;
    if (s >= n) return;
    const int u  = user[s];
    const int it = item[s];

    const float4* ur = (const float4*)(mlp_user_tbl + (size_t)u  * 32);
    const float4* ir = (const float4*)(mlp_item_tbl + (size_t)it * 32);
    const float4* fu = (const float4*)(mf_user_tbl  + (size_t)u  * 16);
    const float4* fi = (const float4*)(mf_item_tbl  + (size_t)it * 16);

    // Prefetch first chunks of both MLP rows (pull both lines toward L1 early).
    float4 a_cur = ur[0];
    float4 ihead = ir[0];

    // ---- GMF branch folded into Wo[0:16] (exact fp32) ----
    float pmf = bo[0];
    #pragma unroll
    for (int q = 0; q < 4; ++q) {
        const float4 a4 = fu[q];
        const float4 b4 = fi[q];
        pmf = fmaf(a4.x * b4.x, Wo[4*q + 0], pmf);
        pmf = fmaf(a4.y * b4.y, Wo[4*q + 1], pmf);
        pmf = fmaf(a4.z * b4.z, Wo[4*q + 2], pmf);
        pmf = fmaf(a4.w * b4.w, Wo[4*q + 3], pmf);
    }

    float h[64];
    #pragma unroll
    for (int j = 0; j < 64; ++j) h[j] = b1[j];

    // ---- layer 1, user half: W1 rows 0..31, 8 chunks x 4 rows ----
    #pragma unroll 1
    for (int kc = 0; kc < 8; ++kc) {
        const float4 a_nxt = ur[(kc + 1) & 7];   // last iter wraps to a hot line (safe, in-bounds)
        const float* w = W1 + kc * 4 * 64;
        #pragma unroll
        for (int j = 0; j < 64; ++j) h[j] = fmaf(a_cur.x, w[j      ], h[j]);
        #pragma unroll
        for (int j = 0; j < 64; ++j) h[j] = fmaf(a_cur.y, w[j +  64], h[j]);
        #pragma unroll
        for (int j = 0; j < 64; ++j) h[j] = fmaf(a_cur.z, w[j + 128], h[j]);
        #pragma unroll
        for (int j = 0; j < 64; ++j) h[j] = fmaf(a_cur.w, w[j + 192], h[j]);
        a_cur = a_nxt;
    }

    // ---- layer 1, item half: W1 rows 32..63 ----
    a_cur = ihead;
    #pragma unroll 1
    for (int kc = 0; kc < 8; ++kc) {
        const float4 a_nxt = ir[(kc + 1) & 7];
        const float* w = W1 + (32 + kc * 4) * 64;
        #pragma unroll
        for (int j = 0; j < 64; ++j) h[j] = fmaf(a_cur.x, w[j      ], h[j]);
        #pragma unroll
        for (int j = 0; j < 64; ++j) h[j] = fmaf(a_cur.y, w[j +  64], h[j]);
        #pragma unroll
        for (int j = 0; j < 64; ++j) h[j] = fmaf(a_cur.z, w[j + 128], h[j]);
        #pragma unroll
        for (int j = 0; j < 64; ++j) h[j] = fmaf(a_cur.w, w[j + 192], h[j]);
        a_cur = a_nxt;
    }

    #pragma unroll
    for (int j = 0; j < 64; ++j) h[j] = fmaxf(h[j], 0.0f);

    // ---- layer 2 + output, j-rolled; W2T rows contiguous; h[k] static ----
    float acc = pmf;
    #pragma unroll 1
    for (int j = 0; j < 32; ++j) {
        const float* w = W2T + j * 64;
        float t0 = b2[j], t1 = 0.0f, t2 = 0.0f, t3 = 0.0f;  // 4 chains for ILP
        #pragma unroll
        for (int k = 0; k < 64; k += 4) {
            t0 = fmaf(h[k + 0], w[k + 0], t0);
            t1 = fmaf(h[k + 1], w[k + 1], t1);
            t2 = fmaf(h[k + 2], w[k + 2], t2);
            t3 = fmaf(h[k + 3], w[k + 3], t3);
        }
        acc = fmaf(fmaxf((t0 + t1) + (t2 + t3), 0.0f), Wo[16 + j], acc);
    }

    out[s] = acc;
}

extern "C" void kernel_launch(void* const* d_in, const int* in_sizes, int n_in,
                              void* d_out, int out_size, void* d_ws, size_t ws_size,
                              hipStream_t stream) {
    const int*   user = (const int*)  d_in[0];
    const int*   item = (const int*)  d_in[1];
    const float* mfu  = (const float*)d_in[2];
    const float* mfi  = (const float*)d_in[3];
    const float* mlu  = (const float*)d_in[4];
    const float* mli  = (const float*)d_in[5];
    const float* W1   = (const float*)d_in[6];
    const float* b1   = (const float*)d_in[7];
    const float* W2   = (const float*)d_in[8];
    const float* b2   = (const float*)d_in[9];
    const float* Wo   = (const float*)d_in[10];
    const float* bo   = (const float*)d_in[11];
    float* out = (float*)d_out;
    float* W2T = (float*)d_ws;   // 32*64 floats = 8 KB of workspace

    w2_transpose<<<1, 64, 0, stream>>>(W2, W2T);

    const int n = in_sizes[0];
    const int blocks = (n + TPB - 1) / TPB;
    neumf_fused<<<blocks, TPB, 0, stream>>>(user, item, mfu, mfi, mlu, mli,
                                            W1, b1, W2T, b2, Wo, bo, out, n);
}

// Round 3
// 373.436 us; speedup vs baseline: 1.6521x; 1.3490x over previous
//
#include <hip/hip_runtime.h>

// NeuMF fused inference via f16 MFMA (16x16x32), one wave = 16 samples/tile.
//
// Structure:
//  - pre-kernel: repack W1 [64,64] and W2 [64,32] (fp32) into f16 MFMA
//    B-fragments in d_ws (frag elem j of lane l = W[kstep*32 + (l>>4)*8 + j][t*16 + (l&15)]).
//  - main kernel: per wave-tile of 16 samples:
//      layer-1 A-frags come DIRECTLY from the gathered mlp rows (k=0..31 = user
//      row, k=32..63 = item row; lane reads row[quad*8..+7]) -> 8 MFMAs.
//      h (bias+relu, f16) round-trips through wave-private LDS into A-layout
//      -> 4 MFMAs for layer 2. Epilogue: relu+b2, dot Wo via LDS partials,
//      lanes 0-15 reduce + GMF (quad-chunked, shfl-xor reduced) -> out.
//  A/B k-pairing is consistent-bijection safe; C/D layout = measured
//  (col=lane&15, row=quad*4+reg), dtype-independent on gfx950.

typedef _Float16 half8 __attribute__((ext_vector_type(8)));
typedef float floatx4 __attribute__((ext_vector_type(4)));

#define WPB 4   // waves per block
#define TPW 4   // tiles per wave

__global__ __launch_bounds__(64) void build_frags(const float* __restrict__ W1,
                                                  const float* __restrict__ W2,
                                                  _Float16* __restrict__ wf) {
    const int l = threadIdx.x;
    const int c = l & 15, q = l >> 4;
    // W1 fragments: [s=0..1][t=0..3], 8 frags of 64 lanes x 8 halves
    #pragma unroll
    for (int s = 0; s < 2; ++s)
        #pragma unroll
        for (int t = 0; t < 4; ++t) {
            _Float16* dst = wf + (size_t)((s * 4 + t) * 64 + l) * 8;
            #pragma unroll
            for (int j = 0; j < 8; ++j) {
                const int k = s * 32 + q * 8 + j;
                const int n = t * 16 + c;
                dst[j] = (_Float16)W1[k * 64 + n];
            }
        }
    // W2 fragments: [s=0..1][t=0..1], 4 frags, at offset 8*64*8
    _Float16* w2b = wf + 8 * 64 * 8;
    #pragma unroll
    for (int s = 0; s < 2; ++s)
        #pragma unroll
        for (int t = 0; t < 2; ++t) {
            _Float16* dst = w2b + (size_t)((s * 2 + t) * 64 + l) * 8;
            #pragma unroll
            for (int j = 0; j < 8; ++j) {
                const int k = s * 32 + q * 8 + j;
                const int n = t * 16 + c;
                dst[j] = (_Float16)W2[k * 32 + n];
            }
        }
}

__global__ __launch_bounds__(256) void neumf_mfma(
    const int* __restrict__ user, const int* __restrict__ item,
    const float* __restrict__ mfu, const float* __restrict__ mfi,
    const float* __restrict__ mlu, const float* __restrict__ mli,
    const _Float16* __restrict__ wf,
    const float* __restrict__ b1, const float* __restrict__ b2,
    const float* __restrict__ Wo, const float* __restrict__ bo,
    float* __restrict__ out, int n)
{
    __shared__ __align__(16) _Float16 x2s[WPB][16 * 72]; // h stage, stride 72 halves (144 B)
    __shared__ __align__(16) float    pss[WPB][16 * 20]; // epilogue partials, stride 20 floats (80 B)

    const int lane = threadIdx.x & 63;
    const int w    = threadIdx.x >> 6;
    const int wave_id = blockIdx.x * WPB + w;
    const int c = lane & 15, q = lane >> 4;

    // ---- resident weight B-fragments (48 VGPRs) ----
    half8 w1f[2][4], w2f[2][2];
    #pragma unroll
    for (int s = 0; s < 2; ++s)
        #pragma unroll
        for (int t = 0; t < 4; ++t)
            w1f[s][t] = *(const half8*)(wf + (size_t)((s * 4 + t) * 64 + lane) * 8);
    const _Float16* w2b = wf + 8 * 64 * 8;
    #pragma unroll
    for (int s = 0; s < 2; ++s)
        #pragma unroll
        for (int t = 0; t < 2; ++t)
            w2f[s][t] = *(const half8*)(w2b + (size_t)((s * 2 + t) * 64 + lane) * 8);

    // per-lane epilogue constants
    const float b1v0 = b1[c], b1v1 = b1[16 + c], b1v2 = b1[32 + c], b1v3 = b1[48 + c];
    const float b2v0 = b2[c], b2v1 = b2[16 + c];
    const float wo2v0 = Wo[16 + c], wo2v1 = Wo[32 + c];
    const float4 wo4 = *(const float4*)(Wo + q * 4);   // GMF chunk of Wo[0:16]
    const float bov = bo[0];

    _Float16* x2 = x2s[w];
    float*    pb = pss[w];

    #pragma unroll 1
    for (int i = 0; i < TPW; ++i) {
        const int base = (wave_id * TPW + i) * 16;
        if (base >= n) break;
        int si = base + c; if (si >= n) si = n - 1;
        const int u  = user[si];
        const int it = item[si];

        // ---- gathers (issued up front; each 128B row line touched once) ----
        const float4* pu = (const float4*)(mlu + (size_t)u  * 32 + q * 8);
        const float4* pi = (const float4*)(mli + (size_t)it * 32 + q * 8);
        const float4 ua = pu[0], ub = pu[1];
        const float4 ia = pi[0], ib = pi[1];
        const float4 gu = *(const float4*)(mfu + (size_t)u  * 16 + q * 4);
        const float4 gi = *(const float4*)(mfi + (size_t)it * 16 + q * 4);

        // ---- layer-1 A-fragments straight from the gathered rows ----
        half8 au, ai;
        au[0] = (_Float16)ua.x; au[1] = (_Float16)ua.y; au[2] = (_Float16)ua.z; au[3] = (_Float16)ua.w;
        au[4] = (_Float16)ub.x; au[5] = (_Float16)ub.y; au[6] = (_Float16)ub.z; au[7] = (_Float16)ub.w;
        ai[0] = (_Float16)ia.x; ai[1] = (_Float16)ia.y; ai[2] = (_Float16)ia.z; ai[3] = (_Float16)ia.w;
        ai[4] = (_Float16)ib.x; ai[5] = (_Float16)ib.y; ai[6] = (_Float16)ib.z; ai[7] = (_Float16)ib.w;

        floatx4 a0 = {0.f,0.f,0.f,0.f}, a1 = {0.f,0.f,0.f,0.f};
        floatx4 a2 = {0.f,0.f,0.f,0.f}, a3 = {0.f,0.f,0.f,0.f};
        a0 = __builtin_amdgcn_mfma_f32_16x16x32_f16(au, w1f[0][0], a0, 0, 0, 0);
        a1 = __builtin_amdgcn_mfma_f32_16x16x32_f16(au, w1f[0][1], a1, 0, 0, 0);
        a2 = __builtin_amdgcn_mfma_f32_16x16x32_f16(au, w1f[0][2], a2, 0, 0, 0);
        a3 = __builtin_amdgcn_mfma_f32_16x16x32_f16(au, w1f[0][3], a3, 0, 0, 0);
        a0 = __builtin_amdgcn_mfma_f32_16x16x32_f16(ai, w1f[1][0], a0, 0, 0, 0);
        a1 = __builtin_amdgcn_mfma_f32_16x16x32_f16(ai, w1f[1][1], a1, 0, 0, 0);
        a2 = __builtin_amdgcn_mfma_f32_16x16x32_f16(ai, w1f[1][2], a2, 0, 0, 0);
        a3 = __builtin_amdgcn_mfma_f32_16x16x32_f16(ai, w1f[1][3], a3, 0, 0, 0);

        // ---- GMF partial (quad-chunked) + cross-quad reduce ----
        float p = gu.x * gi.x * wo4.x + gu.y * gi.y * wo4.y
                + gu.z * gi.z * wo4.z + gu.w * gi.w * wo4.w;
        p += __shfl_xor(p, 16);
        p += __shfl_xor(p, 32);   // all lanes now hold pmf for sample m=c

        // ---- stage h = relu(acc + b1) to LDS as f16 in [m][k] layout ----
        #pragma unroll
        for (int r = 0; r < 4; ++r) {
            const int m = q * 4 + r;     // C/D row = quad*4 + reg (measured)
            x2[m * 72 +  0 + c] = (_Float16)fmaxf(a0[r] + b1v0, 0.f);
            x2[m * 72 + 16 + c] = (_Float16)fmaxf(a1[r] + b1v1, 0.f);
            x2[m * 72 + 32 + c] = (_Float16)fmaxf(a2[r] + b1v2, 0.f);
            x2[m * 72 + 48 + c] = (_Float16)fmaxf(a3[r] + b1v3, 0.f);
        }
        // wave-private LDS; in-order DS pipe + compiler lgkmcnt waits => no barrier

        // ---- layer 2: A-frags from LDS (m = lane&15, k = s*32 + quad*8 + j) ----
        const half8 h0 = *(const half8*)(x2 + c * 72 +  0 + q * 8);
        const half8 h1 = *(const half8*)(x2 + c * 72 + 32 + q * 8);
        floatx4 d0 = {0.f,0.f,0.f,0.f}, d1 = {0.f,0.f,0.f,0.f};
        d0 = __builtin_amdgcn_mfma_f32_16x16x32_f16(h0, w2f[0][0], d0, 0, 0, 0);
        d0 = __builtin_amdgcn_mfma_f32_16x16x32_f16(h1, w2f[1][0], d0, 0, 0, 0);
        d1 = __builtin_amdgcn_mfma_f32_16x16x32_f16(h0, w2f[0][1], d1, 0, 0, 0);
        d1 = __builtin_amdgcn_mfma_f32_16x16x32_f16(h1, w2f[1][1], d1, 0, 0, 0);

        // ---- epilogue: relu(h2 + b2) . Wo[16:48] partials into LDS ----
        #pragma unroll
        for (int r = 0; r < 4; ++r) {
            const float v = fmaxf(d0[r] + b2v0, 0.f) * wo2v0
                          + fmaxf(d1[r] + b2v1, 0.f) * wo2v1;
            pb[(q * 4 + r) * 20 + c] = v;
        }

        if (lane < 16) {
            const float4* row = (const float4*)(pb + lane * 20);
            const float4 r0 = row[0], r1 = row[1], r2 = row[2], r3 = row[3];
            const float s16 = (((r0.x + r0.y) + (r0.z + r0.w)) + ((r1.x + r1.y) + (r1.z + r1.w)))
                            + (((r2.x + r2.y) + (r2.z + r2.w)) + ((r3.x + r3.y) + (r3.z + r3.w)));
            if (base + lane < n)
                out[base + lane] = s16 + p + bov;
        }
    }
}

extern "C" void kernel_launch(void* const* d_in, const int* in_sizes, int n_in,
                              void* d_out, int out_size, void* d_ws, size_t ws_size,
                              hipStream_t stream) {
    const int*   user = (const int*)  d_in[0];
    const int*   item = (const int*)  d_in[1];
    const float* mfu  = (const float*)d_in[2];
    const float* mfi  = (const float*)d_in[3];
    const float* mlu  = (const float*)d_in[4];
    const float* mli  = (const float*)d_in[5];
    const float* W1   = (const float*)d_in[6];
    const float* b1   = (const float*)d_in[7];
    const float* W2   = (const float*)d_in[8];
    const float* b2   = (const float*)d_in[9];
    const float* Wo   = (const float*)d_in[10];
    const float* bo   = (const float*)d_in[11];
    float* out = (float*)d_out;
    _Float16* wf = (_Float16*)d_ws;   // 12 frags x 64 lanes x 8 halves = 12 KB

    build_frags<<<1, 64, 0, stream>>>(W1, W2, wf);

    const int n = in_sizes[0];
    const int tiles  = (n + 15) / 16;
    const int waves  = (tiles + TPW - 1) / TPW;
    const int blocks = (waves + WPB - 1) / WPB;
    neumf_mfma<<<blocks, 256, 0, stream>>>(user, item, mfu, mfi, mlu, mli,
                                           wf, b1, b2, Wo, bo, out, n);
}